// Round 1
// baseline (289.207 us; speedup 1.0000x reference)
//
#include <hip/hip_runtime.h>
#include <hip/hip_bf16.h>
#include <hip/hip_fp16.h>

typedef _Float16 f16x8 __attribute__((ext_vector_type(8)));
typedef _Float16 f16x4 __attribute__((ext_vector_type(4)));
typedef float f32x4 __attribute__((ext_vector_type(4)));

#define MFMA16(a, b, c) __builtin_amdgcn_mfma_f32_16x16x32_f16(a, b, c, 0, 0, 0)

// log2(e) / sqrt(1024)
#define C1 0.045084220027780106f

// ---------------------------------------------------------------------------
// convert f32 -> fp16 for Q, K, Wq, Wk, Wv into one contiguous ws region
// ---------------------------------------------------------------------------
__global__ void cvt_all(const float* __restrict__ Q, const float* __restrict__ K,
                        const float* __restrict__ Wq, const float* __restrict__ Wk,
                        const float* __restrict__ Wv, _Float16* __restrict__ dst) {
    int i = blockIdx.x * blockDim.x + threadIdx.x;  // i indexes groups of 8 f32
    const float* s;
    int off;
    if (i < 524288)       { s = Q;  off = 0;       }
    else if (i < 1048576) { s = K;  off = 524288;  }
    else if (i < 1179648) { s = Wq; off = 1048576; }
    else if (i < 1310720) { s = Wk; off = 1179648; }
    else                  { s = Wv; off = 1310720; }
    int j = i - off;
    float4 a = ((const float4*)s)[2 * j];
    float4 b = ((const float4*)s)[2 * j + 1];
    f16x8 h;
    h[0] = (_Float16)a.x; h[1] = (_Float16)a.y; h[2] = (_Float16)a.z; h[3] = (_Float16)a.w;
    h[4] = (_Float16)b.x; h[5] = (_Float16)b.y; h[6] = (_Float16)b.z; h[7] = (_Float16)b.w;
    ((f16x8*)dst)[i] = h;
}

// ---------------------------------------------------------------------------
// projection GEMM: C[m,n] = sum_k A[m,k] * W[n,k] + bias[n]   (BT gemm)
// z=0: q = Qh*Wq^T, z=1: k = Kh*Wk^T, z=2: v = Kh*Wv^T written TRANSPOSED
//      as vT[b][h][d][n]
// ---------------------------------------------------------------------------
__device__ __forceinline__ void gl_lds16(const void* g, void* l) {
    __builtin_amdgcn_global_load_lds(
        (const __attribute__((address_space(1))) void*)g,
        (__attribute__((address_space(3))) void*)l, 16, 0, 0);
}

__global__ __launch_bounds__(256) void proj_gemm(
    const _Float16* __restrict__ Qh, const _Float16* __restrict__ Kh,
    const _Float16* __restrict__ Wqh, const _Float16* __restrict__ Wkh,
    const _Float16* __restrict__ Wvh,
    const float* __restrict__ bq, const float* __restrict__ bk,
    const float* __restrict__ bv,
    _Float16* __restrict__ qo, _Float16* __restrict__ ko,
    _Float16* __restrict__ vT) {
    const int z = blockIdx.z;
    const _Float16* A = (z == 0) ? Qh : Kh;
    const _Float16* W = (z == 0) ? Wqh : (z == 1 ? Wkh : Wvh);
    const float* bias = (z == 0) ? bq : (z == 1 ? bk : bv);

    __shared__ __align__(16) _Float16 At[128 * 32];
    __shared__ __align__(16) _Float16 Bt[128 * 32];

    const int tid = threadIdx.x;
    const int w = tid >> 6, lane = tid & 63;
    const int g = lane >> 4, c = lane & 15;
    const int m0 = blockIdx.x * 128, n0 = blockIdx.y * 128;
    const int wm = (w & 1) * 64, wn = (w >> 1) * 64;
    // staging: wave w covers tile rows [w*32, w*32+32); lane covers 16B
    const int srow = w * 32 + (lane >> 2);
    const int scol = (lane & 3) * 8;  // in halves

    f32x4 acc[4][4] = {};

    for (int k0 = 0; k0 < 1024; k0 += 32) {
        __syncthreads();
#pragma unroll
        for (int t = 0; t < 2; ++t) {
            int r = srow + t * 16;
            gl_lds16(A + (size_t)(m0 + r) * 1024 + k0 + scol, &At[(w * 2 + t) * 512]);
            gl_lds16(W + (size_t)(n0 + r) * 1024 + k0 + scol, &Bt[(w * 2 + t) * 512]);
        }
        __syncthreads();
        f16x8 af[4], bf[4];
#pragma unroll
        for (int mt = 0; mt < 4; ++mt) af[mt] = *(const f16x8*)&At[(wm + mt * 16 + c) * 32 + g * 8];
#pragma unroll
        for (int nt = 0; nt < 4; ++nt) bf[nt] = *(const f16x8*)&Bt[(wn + nt * 16 + c) * 32 + g * 8];
#pragma unroll
        for (int mt = 0; mt < 4; ++mt)
#pragma unroll
            for (int nt = 0; nt < 4; ++nt)
                acc[mt][nt] = MFMA16(af[mt], bf[nt], acc[mt][nt]);
    }

    if (z != 2) {
        _Float16* C = (z == 0) ? qo : ko;
#pragma unroll
        for (int mt = 0; mt < 4; ++mt)
#pragma unroll
            for (int nt = 0; nt < 4; ++nt) {
                int col = n0 + wn + nt * 16 + c;
                float bb = bias[col];
#pragma unroll
                for (int i = 0; i < 4; ++i) {
                    int row = m0 + wm + mt * 16 + g * 4 + i;
                    C[(size_t)row * 1024 + col] = (_Float16)(acc[mt][nt][i] + bb);
                }
            }
    } else {
#pragma unroll
        for (int mt = 0; mt < 4; ++mt)
#pragma unroll
            for (int nt = 0; nt < 4; ++nt) {
                int col = n0 + wn + nt * 16 + c;
                int hh = col >> 6, dd = col & 63;
                float bb = bias[col];
                int row0 = m0 + wm + mt * 16 + g * 4;
                int bbi = row0 >> 10, nn = row0 & 1023;
                f16x4 pk;
#pragma unroll
                for (int i = 0; i < 4; ++i) pk[i] = (_Float16)(acc[mt][nt][i] + bb);
                *(f16x4*)&vT[((size_t)(bbi * 16 + hh) * 64 + dd) * 1024 + nn] = pk;
            }
    }
}

// ---------------------------------------------------------------------------
// fused attention: per block (qtile of 32 rows, 8 of 16 (b,h) pairs of group b2)
// computes S^T = K q^T (so q-rows live on lane&15), full-row softmax, P via
// LDS, PV with vT, O stores; A_avg accumulated in registers, atomically added
// at the end (exactly 2 contributions per element -> deterministic).
// ---------------------------------------------------------------------------
__global__ __launch_bounds__(512) void attn(
    const _Float16* __restrict__ qh, const _Float16* __restrict__ kh,
    const _Float16* __restrict__ vT, float* __restrict__ O,
    float* __restrict__ Aavg) {
    extern __shared__ __align__(16) char smem[];
    _Float16* P = (_Float16*)smem;                    // [32][1032] halves
    float* red_m = (float*)(smem + 32 * 1032 * 2);    // [8][32]
    float* red_l = red_m + 8 * 32;                    // [8][32]
    float* ored  = red_l + 8 * 32;                    // [2][4][16][64]

    const int tid = threadIdx.x, w = tid >> 6, lane = tid & 63;
    const int g = lane >> 4, c = lane & 15;
    const int q0 = blockIdx.x * 32;
    const int chunk = blockIdx.y, b2 = blockIdx.z;

    float avg[8][2][4] = {};

#pragma unroll 1
    for (int p = 0; p < 8; ++p) {
        const int m = b2 * 16 + chunk * 8 + p;
        const int b = m & 3, h = m >> 2;
        const _Float16* qb = qh + (size_t)b * 1024 * 1024 + h * 64;
        const _Float16* kb = kh + (size_t)b * 1024 * 1024 + h * 64;
        const _Float16* vb = vT + (size_t)(b * 16 + h) * 64 * 1024;

        f16x8 qf[2][2];
#pragma unroll
        for (int qt = 0; qt < 2; ++qt)
#pragma unroll
            for (int ds = 0; ds < 2; ++ds)
                qf[qt][ds] = *(const f16x8*)(qb + (size_t)(q0 + qt * 16 + c) * 1024 + ds * 32 + g * 8);

        // ---- QK^T (S^T fragments: row = k-local, col = q-local) ----
        f32x4 s[8][2];
#pragma unroll
        for (int kt = 0; kt < 8; ++kt) {
            const _Float16* kr = kb + (size_t)(w * 128 + kt * 16 + c) * 1024 + g * 8;
            f16x8 kf0 = *(const f16x8*)(kr);
            f16x8 kf1 = *(const f16x8*)(kr + 32);
#pragma unroll
            for (int qt = 0; qt < 2; ++qt) {
                f32x4 z = {0.f, 0.f, 0.f, 0.f};
                z = MFMA16(kf0, qf[qt][0], z);
                s[kt][qt] = MFMA16(kf1, qf[qt][1], z);
            }
        }

        // ---- softmax: max ----
        float pm0 = -3.0e38f, pm1 = -3.0e38f;
#pragma unroll
        for (int kt = 0; kt < 8; ++kt)
#pragma unroll
            for (int i = 0; i < 4; ++i) {
                pm0 = fmaxf(pm0, s[kt][0][i]);
                pm1 = fmaxf(pm1, s[kt][1][i]);
            }
        pm0 = fmaxf(pm0, __shfl_xor(pm0, 16, 64));
        pm0 = fmaxf(pm0, __shfl_xor(pm0, 32, 64));
        pm1 = fmaxf(pm1, __shfl_xor(pm1, 16, 64));
        pm1 = fmaxf(pm1, __shfl_xor(pm1, 32, 64));
        if (g == 0) { red_m[w * 32 + c] = pm0; red_m[w * 32 + 16 + c] = pm1; }
        __syncthreads();
        float m0r = -3.0e38f, m1r = -3.0e38f;
#pragma unroll
        for (int wv = 0; wv < 8; ++wv) {
            m0r = fmaxf(m0r, red_m[wv * 32 + c]);
            m1r = fmaxf(m1r, red_m[wv * 32 + 16 + c]);
        }

        // ---- exp + sum ----
        float l0 = 0.f, l1 = 0.f;
#pragma unroll
        for (int kt = 0; kt < 8; ++kt)
#pragma unroll
            for (int i = 0; i < 4; ++i) {
                float e0 = exp2f((s[kt][0][i] - m0r) * C1);
                float e1 = exp2f((s[kt][1][i] - m1r) * C1);
                s[kt][0][i] = e0; l0 += e0;
                s[kt][1][i] = e1; l1 += e1;
            }
        l0 += __shfl_xor(l0, 16, 64); l0 += __shfl_xor(l0, 32, 64);
        l1 += __shfl_xor(l1, 16, 64); l1 += __shfl_xor(l1, 32, 64);
        if (g == 0) { red_l[w * 32 + c] = l0; red_l[w * 32 + 16 + c] = l1; }
        __syncthreads();
        float ls0 = 0.f, ls1 = 0.f;
#pragma unroll
        for (int wv = 0; wv < 8; ++wv) { ls0 += red_l[wv * 32 + c]; ls1 += red_l[wv * 32 + 16 + c]; }
        float inv0 = 1.f / ls0, inv1 = 1.f / ls1;
        float iv0 = inv0 * 0.0625f, iv1 = inv1 * 0.0625f;

        // ---- write P (fp16) to LDS + accumulate A_avg in regs ----
#pragma unroll
        for (int kt = 0; kt < 8; ++kt) {
            f16x4 pk0, pk1;
#pragma unroll
            for (int i = 0; i < 4; ++i) {
                pk0[i] = (_Float16)(s[kt][0][i] * inv0);
                pk1[i] = (_Float16)(s[kt][1][i] * inv1);
                avg[kt][0][i] += s[kt][0][i] * iv0;
                avg[kt][1][i] += s[kt][1][i] * iv1;
            }
            int kcol = w * 128 + kt * 16 + g * 4;
            *(f16x4*)&P[(size_t)c * 1032 + kcol] = pk0;
            *(f16x4*)&P[(size_t)(16 + c) * 1032 + kcol] = pk1;
        }
        __syncthreads();

        // ---- PV: wave = (qt half, k quarter); O partial [16 q][64 d] ----
        const int qtw = w & 1, kq = w >> 1;
        f32x4 o[4] = {};
#pragma unroll
        for (int ks = 0; ks < 8; ++ks) {
            int kk = kq * 256 + ks * 32;
            f16x8 pa = *(const f16x8*)&P[(size_t)(qtw * 16 + c) * 1032 + kk + g * 8];
#pragma unroll
            for (int dt = 0; dt < 4; ++dt) {
                f16x8 vf = *(const f16x8*)(vb + (size_t)(dt * 16 + c) * 1024 + kk + g * 8);
                o[dt] = MFMA16(pa, vf, o[dt]);
            }
        }
#pragma unroll
        for (int dt = 0; dt < 4; ++dt)
#pragma unroll
            for (int i = 0; i < 4; ++i)
                ored[((qtw * 4 + kq) * 16 + g * 4 + i) * 64 + dt * 16 + c] = o[dt][i];
        __syncthreads();

        // ---- reduce k-quarters, store O ----
        float* Ob = O + (size_t)b * 1024 * 1024 + (size_t)q0 * 1024 + h * 64;
#pragma unroll
        for (int r = 0; r < 4; ++r) {
            int e = tid + r * 512;
            int qq = e >> 6, dd = e & 63;
            float sum = 0.f;
#pragma unroll
            for (int kq2 = 0; kq2 < 4; ++kq2)
                sum += ored[(((qq >> 4) * 4 + kq2) * 16 + (qq & 15)) * 64 + dd];
            Ob[(size_t)qq * 1024 + dd] = sum;
        }
        __syncthreads();
    }

    // ---- A_avg: one atomic per element, 2 contributions total ----
    float* Ab = Aavg + (size_t)b2 * 1024 * 1024 + (size_t)q0 * 1024;
#pragma unroll
    for (int kt = 0; kt < 8; ++kt)
#pragma unroll
        for (int qt = 0; qt < 2; ++qt) {
            int qq = qt * 16 + c;
            int kk = w * 128 + kt * 16 + g * 4;
#pragma unroll
            for (int i = 0; i < 4; ++i)
                __hip_atomic_fetch_add(&Ab[(size_t)qq * 1024 + kk + i], avg[kt][qt][i],
                                       __ATOMIC_RELAXED, __HIP_MEMORY_SCOPE_AGENT);
        }
}

// ---------------------------------------------------------------------------
extern "C" void kernel_launch(void* const* d_in, const int* in_sizes, int n_in,
                              void* d_out, int out_size, void* d_ws, size_t ws_size,
                              hipStream_t stream) {
    if (ws_size < ((size_t)46 << 20)) return;  // need 46 MB scratch

    const float* Q  = (const float*)d_in[0];
    const float* K  = (const float*)d_in[1];
    const float* Wq = (const float*)d_in[2];
    const float* bq = (const float*)d_in[3];
    const float* Wk = (const float*)d_in[4];
    const float* bk = (const float*)d_in[5];
    const float* Wv = (const float*)d_in[6];
    const float* bv = (const float*)d_in[7];

    char* ws = (char*)d_ws;
    _Float16* Qh  = (_Float16*)(ws);                    //  8 MB
    _Float16* Kh  = (_Float16*)(ws + ((size_t)8 << 20));  //  8 MB
    _Float16* Wqh = (_Float16*)(ws + ((size_t)16 << 20)); //  2 MB
    _Float16* Wkh = (_Float16*)(ws + ((size_t)18 << 20)); //  2 MB
    _Float16* Wvh = (_Float16*)(ws + ((size_t)20 << 20)); //  2 MB
    _Float16* qo  = (_Float16*)(ws + ((size_t)22 << 20)); //  8 MB
    _Float16* ko  = (_Float16*)(ws + ((size_t)30 << 20)); //  8 MB
    _Float16* vT  = (_Float16*)(ws + ((size_t)38 << 20)); //  8 MB

    float* O = (float*)d_out;
    float* Aavg = O + (size_t)4 * 1024 * 1024;

    // 1) convert inputs to fp16 (dst region is contiguous: Qh..Wvh)
    cvt_all<<<dim3(1441792 / 256), 256, 0, stream>>>(Q, K, Wq, Wk, Wv, Qh);

    // 2) three projection GEMMs in one launch (z selects)
    proj_gemm<<<dim3(32, 8, 3), 256, 0, stream>>>(Qh, Kh, Wqh, Wkh, Wvh,
                                                  bq, bk, bv, qo, ko, vT);

    // 3) zero A_avg output region (2 atomic contributions land on it)
    hipMemsetAsync(Aavg, 0, (size_t)4 * 1024 * 1024 * sizeof(float), stream);

    // 4) fused attention
    const int SMEM = 32 * 1032 * 2 + 2 * 8 * 32 * 4 + 2 * 4 * 16 * 64 * 4;  // 100864
    hipFuncSetAttribute((const void*)attn, hipFuncAttributeMaxDynamicSharedMemorySize, SMEM);
    attn<<<dim3(32, 2, 4), 512, SMEM, stream>>>(qo, ko, vT, O, Aavg);
}